// Round 8
// baseline (1256.538 us; speedup 1.0000x reference)
//
// MoCA fused pipeline — round 8: fused batch-loop GEMM+softmax (kills fp32 logit
// round-trip, exact in-register 8-way softmax), ILP-fixed branchless conv3,
// h=512 strips. Fixed 128MiB + 51MB strip region.
#include <hip/hip_runtime.h>

#define Bz 8
#define Sz 2048
#define Dz 1024

typedef __attribute__((ext_vector_type(8))) _Float16 f16x8;
typedef __attribute__((ext_vector_type(4))) short short4v;
typedef __attribute__((ext_vector_type(4))) float f32x4;

__device__ __forceinline__ short f2h(float f) {
    _Float16 h = (_Float16)f;
    return __builtin_bit_cast(short, h);
}
__device__ __forceinline__ float h2f(short s) {
    return (float)__builtin_bit_cast(_Float16, s);
}
__device__ __forceinline__ void gld16(const void* g, void* l) {
    __builtin_amdgcn_global_load_lds(
        (const __attribute__((address_space(1))) void*)g,
        (__attribute__((address_space(3))) void*)l, 16, 0, 0);
}

// ---------------- fused 5x5 convs over x — branchless, load-hoisted ----------------
__global__ __launch_bounds__(256) void conv3_kernel(
    const float* __restrict__ x,
    const float* __restrict__ w1, const float* __restrict__ b1,
    const float* __restrict__ w2, const float* __restrict__ b2,
    short* __restrict__ x16, short* __restrict__ C1f, short* __restrict__ C2f)
{
    __shared__ float w[50];
    __shared__ float bias[2];
    const size_t SD = (size_t)Sz * Dz;
    int tid = threadIdx.x;
    if (tid < 25) w[tid] = w1[tid];
    else if (tid < 50) w[tid] = w2[tid - 25];
    if (tid == 50) { bias[0] = b1[0]; bias[1] = b2[0]; }
    __syncthreads();

    int d4 = tid * 4;
    int y = blockIdx.y;
    int s = ((y & 7) << 8) | (y >> 3);         // XCD-chunked row mapping
    int b = blockIdx.z;
    const float* xb = x + (size_t)b * SD + d4;

    // hoist all 15 loads (clamped rows), then zero invalid rows
    float wv[5][12];
#pragma unroll
    for (int i = 0; i < 5; i++) {
        int ss = s + i - 2;
        int ssc = ss < 0 ? 0 : (ss >= Sz ? Sz - 1 : ss);
        const float* rp = xb + (size_t)ssc * Dz;
        if (d4 > 0) *(float4*)&wv[i][0] = *(const float4*)(rp - 4);
        else { wv[i][0] = wv[i][1] = wv[i][2] = wv[i][3] = 0.f; }
        *(float4*)&wv[i][4] = *(const float4*)rp;
        if (d4 < 1020) *(float4*)&wv[i][8] = *(const float4*)(rp + 4);
        else { wv[i][8] = wv[i][9] = wv[i][10] = wv[i][11] = 0.f; }
        if (ss != ssc) {
#pragma unroll
            for (int q = 0; q < 12; q++) wv[i][q] = 0.f;
        }
    }

    float o1[4] = {}, o2[4] = {};
#pragma unroll
    for (int i = 0; i < 5; i++)
#pragma unroll
        for (int j = 0; j < 5; j++) {
            float c1w = w[i * 5 + j], c2w = w[25 + j * 5 + i];
#pragma unroll
            for (int q = 0; q < 4; q++) {
                float v = wv[i][q + j + 2];
                o1[q] = fmaf(c1w, v, o1[q]);
                o2[q] = fmaf(c2w, v, o2[q]);
            }
        }
    size_t o = (size_t)b * SD + (size_t)s * Dz + d4;
    short4v hx, h1, h2;
#pragma unroll
    for (int q = 0; q < 4; q++) {
        hx[q] = f2h(wv[2][q + 4]);
        h1[q] = f2h(o1[q] + bias[0]);
        h2[q] = f2h(o2[q] + bias[1]);
    }
    *(short4v*)(x16 + o) = hx;
    *(short4v*)(C1f + o) = h1;
    *(short4v*)(C2f + o) = h2;
}

// ---------------- fused conv_g (5x5) + transpose: x[s,d] -> C4T[d,s] fp16 ----------------
__global__ __launch_bounds__(256) void convT_kernel(
    const float* __restrict__ x, const float* __restrict__ w4,
    const float* __restrict__ b4, short* __restrict__ C4T)
{
    __shared__ float xs[68][73];
    __shared__ short ct[64][72];
    __shared__ float w[25];
    __shared__ float bb;
    const size_t SD = (size_t)Sz * Dz;
    int tid = threadIdx.x;
    if (tid < 25) w[tid] = w4[tid];
    if (tid == 25) bb = b4[0];

    int s0 = blockIdx.x * 64, d0 = blockIdx.y * 64, b = blockIdx.z;
    const float* xb = x + (size_t)b * SD;
    for (int k = tid; k < 68 * 68; k += 256) {
        int r = k / 68, c = k - r * 68;
        int gr = s0 - 2 + r, gc = d0 - 2 + c;
        float v = 0.f;
        if (gr >= 0 && gr < Sz && gc >= 0 && gc < Dz) v = xb[(size_t)gr * Dz + gc];
        xs[r][c] = v;
    }
    __syncthreads();

    int sl = tid & 63, dg = tid >> 6;
    float acc[16];
#pragma unroll
    for (int q = 0; q < 16; q++) acc[q] = bb;
#pragma unroll
    for (int i = 0; i < 5; i++) {
        float row[20];
#pragma unroll
        for (int m = 0; m < 20; m++) row[m] = xs[sl + i][dg * 16 + m];
#pragma unroll
        for (int j = 0; j < 5; j++) {
            float wv = w[i * 5 + j];
#pragma unroll
            for (int q = 0; q < 16; q++) acc[q] = fmaf(wv, row[q + j], acc[q]);
        }
    }
#pragma unroll
    for (int q = 0; q < 16; q++) ct[dg * 16 + q][sl] = f2h(acc[q]);
    __syncthreads();

    int dl = tid >> 2, sc = (tid & 3) * 16;
    f16x8 v0 = *(const f16x8*)&ct[dl][sc];
    f16x8 v1 = *(const f16x8*)&ct[dl][sc + 8];
    short* op = C4T + (size_t)b * SD + (size_t)(d0 + dl) * Sz + s0 + sc;
    *(f16x8*)op = v0;
    *(f16x8*)(op + 8) = v1;
}

// ---------------- fused logit GEMM + batch softmax ----------------
// Block computes a 64x64 (s,t) tile for ALL 8 batches of one map (z=0:G, z=1:A),
// then softmax over the 8 in-register values per element, writes fp16 probs.
// 4 waves (2x2, 32x32 each), BK=64 dbuf 2-phase, acc = 8 x f32x4[2][2]/thread.
__global__ __launch_bounds__(256, 2) void logit_sm_kernel(
    const short* __restrict__ Ag, const short* __restrict__ Bg,
    const short* __restrict__ Aa, const short* __restrict__ Ba,
    short* __restrict__ Qg, short* __restrict__ Qa,
    int M, long PS)
{
    __shared__ short sA[2][64 * 64];
    __shared__ short sB[2][64 * 64];
    __shared__ short outb[64][72];

    const size_t SD = (size_t)Sz * Dz;
    const int map = blockIdx.z;
    const short* Abase = map ? Aa : Ag;
    const short* Bbase = map ? Ba : Bg;
    short* Q = map ? Qa : Qg;

    const int m0 = blockIdx.y * 64, n0 = blockIdx.x * 64;
    const int t = threadIdx.x;
    const int lane = t & 63;
    const int w = t >> 6;
    const int wm = w >> 1, wn = w & 1;     // 2x2 wave grid, 32x32 each
    const int fr = lane & 15;
    const int kb = lane >> 4;
    const int swz = (fr & 7) << 4;
    const int sr_ = t >> 3;                // 0..31
    const int scb = (t & 7) * 16;

    f32x4 acc[8][2][2];
#pragma unroll
    for (int b = 0; b < 8; b++)
#pragma unroll
        for (int i = 0; i < 2; i++)
#pragma unroll
            for (int j = 0; j < 2; j++) acc[b][i][j] = (f32x4){0.f, 0.f, 0.f, 0.f};

    auto STAGE = [&](int buf, const short* Ab, const short* Bb, int k0) {
#pragma unroll
        for (int c = 0; c < 2; c++) {
            int r = c * 32 + sr_;
            int rowA = m0 + r; if (rowA > M - 1) rowA = M - 1;
            int cb = scb ^ ((r & 7) << 4);
            gld16((const char*)Ab + ((size_t)rowA * Dz + k0) * 2 + cb,
                  (char*)&sA[buf][0] + c * 4096 + t * 16);
            gld16((const char*)Bb + ((size_t)(n0 + r) * Dz + k0) * 2 + cb,
                  (char*)&sB[buf][0] + c * 4096 + t * 16);
        }
    };

    STAGE(0, Abase, Bbase, 0);
    __syncthreads();
    int cur = 0;
#pragma unroll
    for (int b = 0; b < 8; b++) {
        const short* Ac = Abase + (size_t)b * SD;
        const short* Bc = Bbase + (size_t)b * SD;
        for (int it = 0; it < 16; it++) {
            if (it < 15) STAGE(cur ^ 1, Ac, Bc, (it + 1) * 64);
            else if (b < 7) STAGE(cur ^ 1, Ac + SD, Bc + SD, 0);
            const char* pA = (const char*)&sA[cur][0];
            const char* pB = (const char*)&sB[cur][0];
#pragma unroll
            for (int ks = 0; ks < 2; ks++) {
                f16x8 af[2], bf_[2];
#pragma unroll
                for (int f = 0; f < 2; f++) {
                    int rowA = wm * 32 + f * 16 + fr;
                    af[f] = *(const f16x8*)(pA + rowA * 128 + ((ks * 64 + kb * 16) ^ swz));
                    int rowB = wn * 32 + f * 16 + fr;
                    bf_[f] = *(const f16x8*)(pB + rowB * 128 + ((ks * 64 + kb * 16) ^ swz));
                }
#pragma unroll
                for (int mf = 0; mf < 2; mf++)
#pragma unroll
                    for (int nf = 0; nf < 2; nf++)
                        acc[b][mf][nf] = __builtin_amdgcn_mfma_f32_16x16x32_f16(af[mf], bf_[nf], acc[b][mf][nf], 0, 0, 0);
            }
            __syncthreads();
            cur ^= 1;
        }
    }

    // exact softmax over the 8 batch values per element (in registers)
#pragma unroll
    for (int mf = 0; mf < 2; mf++)
#pragma unroll
        for (int nf = 0; nf < 2; nf++)
#pragma unroll
            for (int rr = 0; rr < 4; rr++) {
                float mx = acc[0][mf][nf][rr];
#pragma unroll
                for (int b = 1; b < 8; b++) mx = fmaxf(mx, acc[b][mf][nf][rr]);
                float sum = 0.f;
#pragma unroll
                for (int b = 0; b < 8; b++) {
                    float e = __expf(acc[b][mf][nf][rr] - mx);
                    acc[b][mf][nf][rr] = e;
                    sum += e;
                }
                float inv = 1.f / sum;
#pragma unroll
                for (int b = 0; b < 8; b++) acc[b][mf][nf][rr] *= inv;
            }

    // per batch: LDS transpose -> coalesced fp16 stores
    int orow = t >> 2, ocb = (t & 3) * 16;
    int grow = m0 + orow;
#pragma unroll
    for (int b = 0; b < 8; b++) {
        __syncthreads();
#pragma unroll
        for (int mf = 0; mf < 2; mf++)
#pragma unroll
            for (int nf = 0; nf < 2; nf++)
#pragma unroll
                for (int rr = 0; rr < 4; rr++)
                    outb[wm * 32 + mf * 16 + kb * 4 + rr][wn * 32 + nf * 16 + fr] =
                        f2h(acc[b][mf][nf][rr]);
        __syncthreads();
        if (grow < M) {
            f16x8 v0 = *(const f16x8*)&outb[orow][ocb];
            f16x8 v1 = *(const f16x8*)&outb[orow][ocb + 8];
            short* op = Q + (size_t)b * PS + (size_t)grow * Sz + n0 + ocb;
            *(f16x8*)op = v0;
            *(f16x8*)(op + 8) = v1;
        }
    }
}

// ---------------- fp16 MFMA NT GEMM — dbuf 2-phase prefetch, dual-map ----------------
template <bool ADD>
__global__ __launch_bounds__(512) void gemm_f16(
    const short* __restrict__ A0, const short* __restrict__ B0,
    const short* __restrict__ A1, const short* __restrict__ B1,
    const float* __restrict__ Src, float* __restrict__ C0, float* __restrict__ C1g,
    int M, int N, int K,
    long sAb, long sBb, long sCb, long sSb)
{
    __shared__ short sA[2][128 * 64];
    __shared__ short sB[2][128 * 64];

    const int zz = blockIdx.z;
    const int map = zz >> 3, bz = zz & 7;
    const short* A = (map ? A1 : A0) + (size_t)bz * sAb;
    const short* B = (map ? B1 : B0) + (size_t)bz * sBb;
    float* C = (map ? C1g : C0) + (size_t)bz * sCb;
    if (ADD) Src += (size_t)bz * sSb;

    const int m0 = blockIdx.y * 128, n0 = blockIdx.x * 128;
    const int t = threadIdx.x;
    const int lane = t & 63;
    const int w = t >> 6;
    const int wm = w >> 2, wn = w & 3;
    const int fr = lane & 15;
    const int kb = lane >> 4;
    const int swz = (fr & 7) << 4;

    const int sr_ = t >> 3;
    const int scb = (t & 7) * 16;

    f32x4 acc[4][2];
#pragma unroll
    for (int i = 0; i < 4; i++)
#pragma unroll
        for (int j = 0; j < 2; j++) acc[i][j] = (f32x4){0.f, 0.f, 0.f, 0.f};

    auto STAGE = [&](int buf, int k0) {
#pragma unroll
        for (int c = 0; c < 2; c++) {
            int r = c * 64 + sr_;
            int rowA = m0 + r; if (rowA > M - 1) rowA = M - 1;
            int cb = scb ^ ((r & 7) << 4);
            gld16((const char*)A + ((size_t)rowA * K + k0) * 2 + cb,
                  (char*)&sA[buf][0] + c * 8192 + t * 16);
            gld16((const char*)B + ((size_t)(n0 + r) * K + k0) * 2 + cb,
                  (char*)&sB[buf][0] + c * 8192 + t * 16);
        }
    };
    auto COMPUTE = [&](int buf) {
#pragma unroll
        for (int ks = 0; ks < 2; ks++) {
            f16x8 af[4], bfr[2];
#pragma unroll
            for (int f = 0; f < 4; f++) {
                int rowA = wm * 64 + f * 16 + fr;
                af[f] = *(const f16x8*)((const char*)&sA[buf][0] + rowA * 128 + ((ks * 64 + kb * 16) ^ swz));
            }
#pragma unroll
            for (int g = 0; g < 2; g++) {
                int rowB = wn * 32 + g * 16 + fr;
                bfr[g] = *(const f16x8*)((const char*)&sB[buf][0] + rowB * 128 + ((ks * 64 + kb * 16) ^ swz));
            }
#pragma unroll
            for (int mf = 0; mf < 4; mf++)
#pragma unroll
                for (int nf = 0; nf < 2; nf++)
                    acc[mf][nf] = __builtin_amdgcn_mfma_f32_16x16x32_f16(af[mf], bfr[nf], acc[mf][nf], 0, 0, 0);
        }
    };

    STAGE(0, 0);
    __syncthreads();
    int cur = 0;
    const int nIter = K / 64;
    for (int it = 1; it < nIter; it++) {
        STAGE(cur ^ 1, it * 64);
        COMPUTE(cur);
        __syncthreads();
        cur ^= 1;
    }
    COMPUTE(cur);

#pragma unroll
    for (int mf = 0; mf < 4; mf++)
#pragma unroll
        for (int nf = 0; nf < 2; nf++) {
            int col = n0 + wn * 32 + nf * 16 + fr;
#pragma unroll
            for (int r = 0; r < 4; r++) {
                int rowg = m0 + wm * 64 + mf * 16 + kb * 4 + r;
                if (rowg < M) {
                    float o = acc[mf][nf][r];
                    if (ADD) o += Src[(size_t)rowg * N + col];
                    C[(size_t)rowg * N + col] = o;
                }
            }
        }
}

// ---------------- moca 5x5 conv over fp16 {G_sm, A_sm} -> fp16 M ----------------
__global__ __launch_bounds__(256) void moca_kernel(
    const short* __restrict__ Gs, const short* __restrict__ As,
    const float* __restrict__ w3, const float* __restrict__ b3,
    short* __restrict__ Mout,
    int o0, int rlo, long psIn, long psOut)
{
    __shared__ float w[50];
    __shared__ float bb;
    int tid = threadIdx.x;
    if (tid < 50) w[tid] = w3[tid];
    if (tid == 50) bb = b3[0];
    __syncthreads();

    int t8 = tid * 8;
    int so = blockIdx.y, b = blockIdx.z;
    int s = o0 + so;
    const short* Gp = Gs + (size_t)b * psIn;
    const short* Ap = As + (size_t)b * psIn;

    float acc[8];
#pragma unroll
    for (int q = 0; q < 8; q++) acc[q] = bb;

#pragma unroll
    for (int i = 0; i < 5; i++) {
        int sr = s + i - 2;
        if (sr < 0 || sr >= Sz) continue;
        size_t ro = (size_t)(sr - rlo) * Sz;
        float gw[16], aw[16];
#pragma unroll
        for (int g = 0; g < 4; g++) {
            int c0 = t8 - 4 + g * 4;
            if (c0 >= 0 && c0 + 3 < Sz) {
                short4v gv = *(const short4v*)(Gp + ro + c0);
                short4v av = *(const short4v*)(Ap + ro + c0);
#pragma unroll
                for (int e = 0; e < 4; e++) { gw[g * 4 + e] = h2f(gv[e]); aw[g * 4 + e] = h2f(av[e]); }
            } else {
#pragma unroll
                for (int e = 0; e < 4; e++) { gw[g * 4 + e] = 0.f; aw[g * 4 + e] = 0.f; }
            }
        }
#pragma unroll
        for (int j = 0; j < 5; j++) {
            float wg = w[i * 5 + j], wa = w[25 + i * 5 + j];
#pragma unroll
            for (int q = 0; q < 8; q++)
                acc[q] = fmaf(wg, gw[q + j + 2], fmaf(wa, aw[q + j + 2], acc[q]));
        }
    }
    short4v r0, r1;
#pragma unroll
    for (int q = 0; q < 4; q++) { r0[q] = f2h(acc[q]); r1[q] = f2h(acc[q + 4]); }
    short* op = Mout + (size_t)b * psOut + (size_t)so * Sz + t8;
    *(short4v*)op = r0;
    *(short4v*)(op + 4) = r1;
}

// ---------------- host ----------------
extern "C" void kernel_launch(void* const* d_in, const int* in_sizes, int n_in,
                              void* d_out, int out_size, void* d_ws, size_t ws_size,
                              hipStream_t stream)
{
    const float* x  = (const float*)d_in[0];
    const float* w1 = (const float*)d_in[1];
    const float* b1 = (const float*)d_in[2];
    const float* w2 = (const float*)d_in[3];
    const float* b2 = (const float*)d_in[4];
    const float* w3 = (const float*)d_in[5];
    const float* b3 = (const float*)d_in[6];
    const float* w4 = (const float*)d_in[7];
    const float* b4 = (const float*)d_in[8];
    float* out = (float*)d_out;

    const size_t SD = (size_t)Sz * Dz;
    const size_t BSD2 = (size_t)Bz * SD * 2;     // 32MiB per fp16 [B,S,D] buffer

    char* ws = (char*)d_ws;
    short* x16 = (short*)(ws);
    short* C1f = (short*)(ws + 1 * BSD2);
    short* C2f = (short*)(ws + 2 * BSD2);
    short* C4T = (short*)(ws + 3 * BSD2);
    char* strip0 = ws + 4 * BSD2;                // 128MiB fixed

    // strip region (PS = 516 rows): Gsm, Asm, Mf fp16 = 50.6MB
    const size_t PS = (size_t)516 * Sz;
    short* Gsm = (short*)strip0;
    short* Asm = Gsm + (size_t)Bz * PS;
    short* Mf  = Asm + (size_t)Bz * PS;

    conv3_kernel<<<dim3(1, Sz, Bz), 256, 0, stream>>>(
        x, w1, b1, w2, b2, x16, C1f, C2f);
    convT_kernel<<<dim3(Sz / 64, Dz / 64, Bz), 256, 0, stream>>>(x, w4, b4, C4T);

    const int o0s[5] = { 0, 512, 1024, 1536, 2048 };
    for (int k = 0; k < 4; k++) {
        int o0 = o0s[k], o1 = o0s[k + 1];
        int hcur = o1 - o0;                      // 512
        int rlo = o0 - 2; if (rlo < 0) rlo = 0;
        int rhi = o1 + 2; if (rhi > Sz) rhi = Sz;
        int nv = rhi - rlo;                      // 514 / 516

        // fused logit GEMM + batch softmax -> Gsm, Asm (fp16 probs)
        dim3 gl(Sz / 64, 9, 2);
        logit_sm_kernel<<<gl, 256, 0, stream>>>(
            x16 + (size_t)rlo * Dz, x16,
            C1f + (size_t)rlo * Dz, C2f,
            Gsm, Asm, nv, (long)PS);

        // moca -> Mf
        moca_kernel<<<dim3(1, hcur, Bz), 256, 0, stream>>>(
            Gsm, Asm, w3, b3, Mf, o0, rlo, (long)PS, (long)((size_t)hcur * Sz));

        // Wz = M @ C4T^T + x -> out
        dim3 g2(Dz / 128, hcur / 128, 8);
        gemm_f16<true><<<g2, 512, 0, stream>>>(
            Mf, C4T, Mf, C4T,
            x + (size_t)o0 * Dz, out + (size_t)o0 * Dz, out + (size_t)o0 * Dz,
            hcur, Dz, Sz, (long)((size_t)hcur * Sz), (long)SD, (long)SD, (long)SD);
    }
}

// Round 9
// 642.976 us; speedup vs baseline: 1.9543x; 1.9543x over previous
//
// MoCA fused pipeline — round 9: round-7 skeleton + fp16 logits (G-diag offset),
// in-place batch softmax, h=1024 strips (2), branchless conv3. 235MB ws.
#include <hip/hip_runtime.h>

#define Bz 8
#define Sz 2048
#define Dz 1024

typedef __attribute__((ext_vector_type(8))) _Float16 f16x8;
typedef __attribute__((ext_vector_type(8))) short short8v;
typedef __attribute__((ext_vector_type(4))) short short4v;
typedef __attribute__((ext_vector_type(4))) float f32x4;

__device__ __forceinline__ short f2h(float f) {
    _Float16 h = (_Float16)f;
    return __builtin_bit_cast(short, h);
}
__device__ __forceinline__ float h2f(short s) {
    return (float)__builtin_bit_cast(_Float16, s);
}
__device__ __forceinline__ void gld16(const void* g, void* l) {
    __builtin_amdgcn_global_load_lds(
        (const __attribute__((address_space(1))) void*)g,
        (__attribute__((address_space(3))) void*)l, 16, 0, 0);
}

// ---------------- fused 5x5 convs over x — branchless, load-hoisted, XCD-chunked ----------------
__global__ __launch_bounds__(256) void conv3_kernel(
    const float* __restrict__ x,
    const float* __restrict__ w1, const float* __restrict__ b1,
    const float* __restrict__ w2, const float* __restrict__ b2,
    short* __restrict__ x16, short* __restrict__ C1f, short* __restrict__ C2f)
{
    __shared__ float w[50];
    __shared__ float bias[2];
    const size_t SD = (size_t)Sz * Dz;
    int tid = threadIdx.x;
    if (tid < 25) w[tid] = w1[tid];
    else if (tid < 50) w[tid] = w2[tid - 25];
    if (tid == 50) { bias[0] = b1[0]; bias[1] = b2[0]; }
    __syncthreads();

    int d4 = tid * 4;
    int y = blockIdx.y;
    int s = ((y & 7) << 8) | (y >> 3);         // XCD-chunked row mapping
    int b = blockIdx.z;
    const float* xb = x + (size_t)b * SD + d4;

    float wv[5][12];
#pragma unroll
    for (int i = 0; i < 5; i++) {
        int ss = s + i - 2;
        int ssc = ss < 0 ? 0 : (ss >= Sz ? Sz - 1 : ss);
        const float* rp = xb + (size_t)ssc * Dz;
        if (d4 > 0) *(float4*)&wv[i][0] = *(const float4*)(rp - 4);
        else { wv[i][0] = wv[i][1] = wv[i][2] = wv[i][3] = 0.f; }
        *(float4*)&wv[i][4] = *(const float4*)rp;
        if (d4 < 1020) *(float4*)&wv[i][8] = *(const float4*)(rp + 4);
        else { wv[i][8] = wv[i][9] = wv[i][10] = wv[i][11] = 0.f; }
        if (ss != ssc) {
#pragma unroll
            for (int q = 0; q < 12; q++) wv[i][q] = 0.f;
        }
    }

    float o1[4] = {}, o2[4] = {};
#pragma unroll
    for (int i = 0; i < 5; i++)
#pragma unroll
        for (int j = 0; j < 5; j++) {
            float c1w = w[i * 5 + j], c2w = w[25 + j * 5 + i];
#pragma unroll
            for (int q = 0; q < 4; q++) {
                float v = wv[i][q + j + 2];
                o1[q] = fmaf(c1w, v, o1[q]);
                o2[q] = fmaf(c2w, v, o2[q]);
            }
        }
    size_t o = (size_t)b * SD + (size_t)s * Dz + d4;
    short4v hx, h1, h2;
#pragma unroll
    for (int q = 0; q < 4; q++) {
        hx[q] = f2h(wv[2][q + 4]);
        h1[q] = f2h(o1[q] + bias[0]);
        h2[q] = f2h(o2[q] + bias[1]);
    }
    *(short4v*)(x16 + o) = hx;
    *(short4v*)(C1f + o) = h1;
    *(short4v*)(C2f + o) = h2;
}

// ---------------- fused conv_g (5x5) + transpose: x[s,d] -> C4T[d,s] fp16 ----------------
__global__ __launch_bounds__(256) void convT_kernel(
    const float* __restrict__ x, const float* __restrict__ w4,
    const float* __restrict__ b4, short* __restrict__ C4T)
{
    __shared__ float xs[68][73];
    __shared__ short ct[64][72];
    __shared__ float w[25];
    __shared__ float bb;
    const size_t SD = (size_t)Sz * Dz;
    int tid = threadIdx.x;
    if (tid < 25) w[tid] = w4[tid];
    if (tid == 25) bb = b4[0];

    int s0 = blockIdx.x * 64, d0 = blockIdx.y * 64, b = blockIdx.z;
    const float* xb = x + (size_t)b * SD;
    for (int k = tid; k < 68 * 68; k += 256) {
        int r = k / 68, c = k - r * 68;
        int gr = s0 - 2 + r, gc = d0 - 2 + c;
        float v = 0.f;
        if (gr >= 0 && gr < Sz && gc >= 0 && gc < Dz) v = xb[(size_t)gr * Dz + gc];
        xs[r][c] = v;
    }
    __syncthreads();

    int sl = tid & 63, dg = tid >> 6;
    float acc[16];
#pragma unroll
    for (int q = 0; q < 16; q++) acc[q] = bb;
#pragma unroll
    for (int i = 0; i < 5; i++) {
        float row[20];
#pragma unroll
        for (int m = 0; m < 20; m++) row[m] = xs[sl + i][dg * 16 + m];
#pragma unroll
        for (int j = 0; j < 5; j++) {
            float wv = w[i * 5 + j];
#pragma unroll
            for (int q = 0; q < 16; q++) acc[q] = fmaf(wv, row[q + j], acc[q]);
        }
    }
#pragma unroll
    for (int q = 0; q < 16; q++) ct[dg * 16 + q][sl] = f2h(acc[q]);
    __syncthreads();

    int dl = tid >> 2, sc = (tid & 3) * 16;
    f16x8 v0 = *(const f16x8*)&ct[dl][sc];
    f16x8 v1 = *(const f16x8*)&ct[dl][sc + 8];
    short* op = C4T + (size_t)b * SD + (size_t)(d0 + dl) * Sz + s0 + sc;
    *(f16x8*)op = v0;
    *(f16x8*)(op + 8) = v1;
}

// ---------------- logit GEMM: fp16 out, dual-map, dbuf 2-phase ----------------
// z<8: G-map (x16 . x16^T, minus 1024 on global diagonal), z>=8: A-map (C1f . C2f^T).
// 128x128 tile, BK=64, 8 waves (2Mx4N, 64x32 each), global_load_lds + XOR swizzle.
__global__ __launch_bounds__(512) void logit_f16(
    const short* __restrict__ Ag, const short* __restrict__ Bg,
    const short* __restrict__ Aa, const short* __restrict__ Ba,
    short* __restrict__ Qg, short* __restrict__ Qa,
    int M, int rlo, long PS)
{
    __shared__ short sA[2][128 * 64];
    __shared__ short sB[2][128 * 64];

    const size_t SD = (size_t)Sz * Dz;
    const int zz = blockIdx.z;
    const int map = zz >> 3, bz = zz & 7;
    const short* A = (map ? Aa : Ag) + (size_t)bz * SD;
    const short* B = (map ? Ba : Bg) + (size_t)bz * SD;
    short* Q = (map ? Qa : Qg) + (size_t)bz * PS;

    const int m0 = blockIdx.y * 128, n0 = blockIdx.x * 128;
    const int t = threadIdx.x;
    const int lane = t & 63;
    const int w = t >> 6;
    const int wm = w >> 2, wn = w & 3;
    const int fr = lane & 15;
    const int kb = lane >> 4;
    const int swz = (fr & 7) << 4;
    const int sr_ = t >> 3;
    const int scb = (t & 7) * 16;

    f32x4 acc[4][2];
#pragma unroll
    for (int i = 0; i < 4; i++)
#pragma unroll
        for (int j = 0; j < 2; j++) acc[i][j] = (f32x4){0.f, 0.f, 0.f, 0.f};

    auto STAGE = [&](int buf, int k0) {
#pragma unroll
        for (int c = 0; c < 2; c++) {
            int r = c * 64 + sr_;
            int rowA = m0 + r; if (rowA > M - 1) rowA = M - 1;
            int cb = scb ^ ((r & 7) << 4);
            gld16((const char*)A + ((size_t)rowA * Dz + k0) * 2 + cb,
                  (char*)&sA[buf][0] + c * 8192 + t * 16);
            gld16((const char*)B + ((size_t)(n0 + r) * Dz + k0) * 2 + cb,
                  (char*)&sB[buf][0] + c * 8192 + t * 16);
        }
    };
    auto COMPUTE = [&](int buf) {
#pragma unroll
        for (int ks = 0; ks < 2; ks++) {
            f16x8 af[4], bfr[2];
#pragma unroll
            for (int f = 0; f < 4; f++) {
                int rowA = wm * 64 + f * 16 + fr;
                af[f] = *(const f16x8*)((const char*)&sA[buf][0] + rowA * 128 + ((ks * 64 + kb * 16) ^ swz));
            }
#pragma unroll
            for (int g = 0; g < 2; g++) {
                int rowB = wn * 32 + g * 16 + fr;
                bfr[g] = *(const f16x8*)((const char*)&sB[buf][0] + rowB * 128 + ((ks * 64 + kb * 16) ^ swz));
            }
#pragma unroll
            for (int mf = 0; mf < 4; mf++)
#pragma unroll
                for (int nf = 0; nf < 2; nf++)
                    acc[mf][nf] = __builtin_amdgcn_mfma_f32_16x16x32_f16(af[mf], bfr[nf], acc[mf][nf], 0, 0, 0);
        }
    };

    STAGE(0, 0);
    __syncthreads();
    int cur = 0;
    for (int it = 1; it < Dz / 64; it++) {
        STAGE(cur ^ 1, it * 64);
        COMPUTE(cur);
        __syncthreads();
        cur ^= 1;
    }
    COMPUTE(cur);

#pragma unroll
    for (int mf = 0; mf < 4; mf++)
#pragma unroll
        for (int nf = 0; nf < 2; nf++) {
            int col = n0 + wn * 32 + nf * 16 + fr;
#pragma unroll
            for (int r = 0; r < 4; r++) {
                int rowg = m0 + wm * 64 + mf * 16 + kb * 4 + r;
                if (rowg < M) {
                    float o = acc[mf][nf][r];
                    // G map: subtract 1024 on the global diagonal so the ~1024-magnitude
                    // self-similarity logits stay fp16-accurate (softmax shift-invariant).
                    if (map == 0 && rlo + rowg == col) o -= 1024.f;
                    Q[(size_t)rowg * Sz + col] = f2h(o);
                }
            }
        }
}

// ---------------- in-place batch softmax on fp16 logits (both maps) ----------------
__global__ __launch_bounds__(256) void softmax_ip(
    short* __restrict__ Qg, short* __restrict__ Qa, int nElem, long ps)
{
    int i8 = (blockIdx.x * 256 + threadIdx.x) * 8;
    if (i8 >= nElem) return;
    short* Q = blockIdx.z ? Qa : Qg;

    short8v v[Bz];
    float f[Bz][8];
#pragma unroll
    for (int b = 0; b < Bz; b++) {
        v[b] = *(const short8v*)(Q + i8 + (size_t)b * ps);
#pragma unroll
        for (int e = 0; e < 8; e++) f[b][e] = h2f(v[b][e]);
    }
#pragma unroll
    for (int e = 0; e < 8; e++) {
        float mx = f[0][e];
#pragma unroll
        for (int b = 1; b < Bz; b++) mx = fmaxf(mx, f[b][e]);
        float sum = 0.f;
#pragma unroll
        for (int b = 0; b < Bz; b++) { f[b][e] = __expf(f[b][e] - mx); sum += f[b][e]; }
        float inv = 1.f / sum;
#pragma unroll
        for (int b = 0; b < Bz; b++) v[b][e] = f2h(f[b][e] * inv);
    }
#pragma unroll
    for (int b = 0; b < Bz; b++)
        *(short8v*)(Q + i8 + (size_t)b * ps) = v[b];
}

// ---------------- moca 5x5 conv over fp16 probs {G, A} -> fp16 M ----------------
__global__ __launch_bounds__(256) void moca_kernel(
    const short* __restrict__ Gs, const short* __restrict__ As,
    const float* __restrict__ w3, const float* __restrict__ b3,
    short* __restrict__ Mout,
    int o0, int rlo, long psIn, long psOut)
{
    __shared__ float w[50];
    __shared__ float bb;
    int tid = threadIdx.x;
    if (tid < 50) w[tid] = w3[tid];
    if (tid == 50) bb = b3[0];
    __syncthreads();

    int t8 = tid * 8;
    int so = blockIdx.y, b = blockIdx.z;
    int s = o0 + so;
    const short* Gp = Gs + (size_t)b * psIn;
    const short* Ap = As + (size_t)b * psIn;

    float acc[8];
#pragma unroll
    for (int q = 0; q < 8; q++) acc[q] = bb;

#pragma unroll
    for (int i = 0; i < 5; i++) {
        int sr = s + i - 2;
        if (sr < 0 || sr >= Sz) continue;
        size_t ro = (size_t)(sr - rlo) * Sz;
        float gw[16], aw[16];
#pragma unroll
        for (int g = 0; g < 4; g++) {
            int c0 = t8 - 4 + g * 4;
            if (c0 >= 0 && c0 + 3 < Sz) {
                short4v gv = *(const short4v*)(Gp + ro + c0);
                short4v av = *(const short4v*)(Ap + ro + c0);
#pragma unroll
                for (int e = 0; e < 4; e++) { gw[g * 4 + e] = h2f(gv[e]); aw[g * 4 + e] = h2f(av[e]); }
            } else {
#pragma unroll
                for (int e = 0; e < 4; e++) { gw[g * 4 + e] = 0.f; aw[g * 4 + e] = 0.f; }
            }
        }
#pragma unroll
        for (int j = 0; j < 5; j++) {
            float wg = w[i * 5 + j], wa = w[25 + i * 5 + j];
#pragma unroll
            for (int q = 0; q < 8; q++)
                acc[q] = fmaf(wg, gw[q + j + 2], fmaf(wa, aw[q + j + 2], acc[q]));
        }
    }
    short4v r0, r1;
#pragma unroll
    for (int q = 0; q < 4; q++) { r0[q] = f2h(acc[q]); r1[q] = f2h(acc[q + 4]); }
    short* op = Mout + (size_t)b * psOut + (size_t)so * Sz + t8;
    *(short4v*)op = r0;
    *(short4v*)(op + 4) = r1;
}

// ---------------- Wz GEMM: M @ C4T^T + x, fp32 out, dbuf 2-phase ----------------
__global__ __launch_bounds__(512) void gemm_wz(
    const short* __restrict__ A, const short* __restrict__ B,
    const float* __restrict__ Src, float* __restrict__ C,
    int M, long sAb)
{
    __shared__ short sA[2][128 * 64];
    __shared__ short sB[2][128 * 64];

    const size_t SD = (size_t)Sz * Dz;
    const int bz = blockIdx.z;
    A += (size_t)bz * sAb;
    B += (size_t)bz * SD;
    Src += (size_t)bz * SD;
    C += (size_t)bz * SD;

    const int m0 = blockIdx.y * 128, n0 = blockIdx.x * 128;
    const int t = threadIdx.x;
    const int lane = t & 63;
    const int w = t >> 6;
    const int wm = w >> 2, wn = w & 3;
    const int fr = lane & 15;
    const int kb = lane >> 4;
    const int swz = (fr & 7) << 4;
    const int sr_ = t >> 3;
    const int scb = (t & 7) * 16;

    f32x4 acc[4][2];
#pragma unroll
    for (int i = 0; i < 4; i++)
#pragma unroll
        for (int j = 0; j < 2; j++) acc[i][j] = (f32x4){0.f, 0.f, 0.f, 0.f};

    auto STAGE = [&](int buf, int k0) {
#pragma unroll
        for (int c = 0; c < 2; c++) {
            int r = c * 64 + sr_;
            int rowA = m0 + r; if (rowA > M - 1) rowA = M - 1;
            int cb = scb ^ ((r & 7) << 4);
            gld16((const char*)A + ((size_t)rowA * Sz + k0) * 2 + cb,
                  (char*)&sA[buf][0] + c * 8192 + t * 16);
            gld16((const char*)B + ((size_t)(n0 + r) * Sz + k0) * 2 + cb,
                  (char*)&sB[buf][0] + c * 8192 + t * 16);
        }
    };
    auto COMPUTE = [&](int buf) {
#pragma unroll
        for (int ks = 0; ks < 2; ks++) {
            f16x8 af[4], bfr[2];
#pragma unroll
            for (int f = 0; f < 4; f++) {
                int rowA = wm * 64 + f * 16 + fr;
                af[f] = *(const f16x8*)((const char*)&sA[buf][0] + rowA * 128 + ((ks * 64 + kb * 16) ^ swz));
            }
#pragma unroll
            for (int g = 0; g < 2; g++) {
                int rowB = wn * 32 + g * 16 + fr;
                bfr[g] = *(const f16x8*)((const char*)&sB[buf][0] + rowB * 128 + ((ks * 64 + kb * 16) ^ swz));
            }
#pragma unroll
            for (int mf = 0; mf < 4; mf++)
#pragma unroll
                for (int nf = 0; nf < 2; nf++)
                    acc[mf][nf] = __builtin_amdgcn_mfma_f32_16x16x32_f16(af[mf], bfr[nf], acc[mf][nf], 0, 0, 0);
        }
    };

    STAGE(0, 0);
    __syncthreads();
    int cur = 0;
    for (int it = 1; it < Sz / 64; it++) {
        STAGE(cur ^ 1, it * 64);
        COMPUTE(cur);
        __syncthreads();
        cur ^= 1;
    }
    COMPUTE(cur);

#pragma unroll
    for (int mf = 0; mf < 4; mf++)
#pragma unroll
        for (int nf = 0; nf < 2; nf++) {
            int col = n0 + wn * 32 + nf * 16 + fr;
#pragma unroll
            for (int r = 0; r < 4; r++) {
                int rowg = m0 + wm * 64 + mf * 16 + kb * 4 + r;
                if (rowg < M)
                    C[(size_t)rowg * Dz + col] = acc[mf][nf][r] + Src[(size_t)rowg * Dz + col];
            }
        }
}

// ---------------- host ----------------
extern "C" void kernel_launch(void* const* d_in, const int* in_sizes, int n_in,
                              void* d_out, int out_size, void* d_ws, size_t ws_size,
                              hipStream_t stream)
{
    const float* x  = (const float*)d_in[0];
    const float* w1 = (const float*)d_in[1];
    const float* b1 = (const float*)d_in[2];
    const float* w2 = (const float*)d_in[3];
    const float* b2 = (const float*)d_in[4];
    const float* w3 = (const float*)d_in[5];
    const float* b3 = (const float*)d_in[6];
    const float* w4 = (const float*)d_in[7];
    const float* b4 = (const float*)d_in[8];
    float* out = (float*)d_out;

    const size_t SD = (size_t)Sz * Dz;
    const size_t BSD2 = (size_t)Bz * SD * 2;     // 32MiB per fp16 [B,S,D] buffer

    char* ws = (char*)d_ws;
    short* x16 = (short*)(ws);
    short* C1f = (short*)(ws + 1 * BSD2);
    short* C2f = (short*)(ws + 2 * BSD2);
    short* C4T = (short*)(ws + 3 * BSD2);
    char* strip0 = ws + 4 * BSD2;                // 134.2MB fixed

    // strips of h=1024: logit rows nv=1026 per strip. PS plane = 1026*2048 elems.
    // Fg, Fa fp16 logits->probs (in-place softmax) 33.6MB each; Mf fp16 33.6MB. 235MB total.
    const int NV = 1026;
    const size_t PS = (size_t)NV * Sz;
    short* Fg = (short*)strip0;
    short* Fa = Fg + (size_t)Bz * PS;
    short* Mf = Fa + (size_t)Bz * PS;
    const size_t PSM = (size_t)1024 * Sz;

    conv3_kernel<<<dim3(1, Sz, Bz), 256, 0, stream>>>(
        x, w1, b1, w2, b2, x16, C1f, C2f);
    convT_kernel<<<dim3(Sz / 64, Dz / 64, Bz), 256, 0, stream>>>(x, w4, b4, C4T);

    for (int k = 0; k < 2; k++) {
        int o0 = k * 1024;
        int rlo = (k == 0) ? 0 : 1022;           // 1026 logit rows cover output+halo

        // logit GEMMs (both maps, fp16 out, G-diag offset) -> Fg, Fa
        dim3 gl(Sz / 128, (NV + 127) / 128, 16);
        logit_f16<<<gl, 512, 0, stream>>>(
            x16 + (size_t)rlo * Dz, x16,
            C1f + (size_t)rlo * Dz, C2f,
            Fg, Fa, NV, rlo, (long)PS);

        // in-place batch softmax on both maps
        int ne = NV * Sz;
        dim3 gs((ne / 8 + 255) / 256, 1, 2);
        softmax_ip<<<gs, 256, 0, stream>>>(Fg, Fa, ne, (long)PS);

        // moca 5x5 over probs -> Mf
        moca_kernel<<<dim3(1, 1024, Bz), 256, 0, stream>>>(
            Fg, Fa, w3, b3, Mf, o0, rlo, (long)PS, (long)PSM);

        // Wz = M @ C4T^T + x -> out
        dim3 g2(Dz / 128, 1024 / 128, Bz);
        gemm_wz<<<g2, 512, 0, stream>>>(
            Mf, C4T, x + (size_t)o0 * Dz, out + (size_t)o0 * Dz,
            1024, (long)PSM);
    }
}